// Round 1
// baseline (6441.615 us; speedup 1.0000x reference)
//
#include <hip/hip_runtime.h>
#include <math.h>

#define VOCAB 8000
#define DD 256
#define HH 256
#define BBATCH 16
#define TLEN 128
#define GG 1024   /* 4H */
#define NN 2048   /* B*T */

// ---- workspace offsets (in floats) ----
#define OFF_WENCT 0ul         /* [512][1024]            524288 */
#define OFF_XP0   524288ul    /* [2][1024]                2048 */
#define OFF_HENC  526336ul    /* [2 parity][2 d][16][256] 16384 */
#define OFF_CENC  542720ul    /* [2 d][16][256]           8192 */
#define OFF_H0    550912ul    /* [2][2048][256]        1048576 */
#define OFF_DECX  1599488ul   /* [2][3][2048][256]     3145728 */
#define OFF_CDEC  4745216ul   /* [2][2048][256]        1048576 */
#define OFF_HS    5793792ul   /* [2][4][2048][256]     4194304 */
#define OFF_GBUF  9988096ul   /* [2][2048][1024]       4194304 */
#define OFF_LOGZ  14182400ul  /* [2][4][2048]            16384 */
#define OFF_GCH   14198784ul  /* [2][3][2048]            12288 */
#define OFF_GTG   14211072ul  /* [2][3][2048]            12288 */
#define OFF_P     14223360ul  /* [128][3][16]             6144 */
#define OFF_WTOK  14229504ul  /* int [2][3][2048]        12288 */

__device__ __forceinline__ float sigf(float x) { return 1.0f / (1.0f + __expf(-x)); }
__device__ __forceinline__ float tanhsafe(float x) {
    x = fminf(15.0f, fmaxf(-15.0f, x));
    float e = __expf(2.0f * x);
    return (e - 1.0f) / (e + 1.0f);
}

// ---------------- setup kernels ----------------

__global__ __launch_bounds__(256) void k_zero(float* __restrict__ p, int n) {
    int i = blockIdx.x * 256 + threadIdx.x;
    if (i < n) p[i] = 0.0f;
}

// WencT[k][r]: k<256 -> enc_Whh[r][k], else enc_Wih[r][k-256]
__global__ __launch_bounds__(256) void k_wenct(const float* __restrict__ Whh,
                                               const float* __restrict__ Wih,
                                               float* __restrict__ WencT) {
    int idx = blockIdx.x * 256 + threadIdx.x;  // 512*1024
    int k = idx >> 10, r = idx & 1023;
    WencT[idx] = (k < 256) ? Whh[r * 256 + k] : Wih[r * 256 + (k - 256)];
}

// xp0[d][r] = emb[PART=0] . Wih_d[r]
__global__ __launch_bounds__(256) void k_xp0(const float* __restrict__ emb,
                                             const float* __restrict__ Wihf,
                                             const float* __restrict__ Wihb,
                                             float* __restrict__ xp0) {
    int idx = blockIdx.x * 256 + threadIdx.x;  // 2048
    int d = idx >> 10, r = idx & 1023;
    const float* Wih = d ? Wihb : Wihf;
    float acc = 0.0f;
    for (int k = 0; k < 256; ++k) acc = fmaf(emb[k], Wih[r * 256 + k], acc);
    xp0[idx] = acc;
}

// decX[d][s][n][k] = emb[win_d[n][s]][k]; winTok[d][s][n] = token
__global__ __launch_bounds__(256) void k_decx(const int* __restrict__ S,
                                              const float* __restrict__ emb,
                                              float* __restrict__ decX,
                                              int* __restrict__ winTok) {
    int flat = blockIdx.x * 256 + threadIdx.x;  // 2*3*2048*256
    int k = flat & 255;
    int rest = flat >> 8;
    int n = rest & 2047; rest >>= 11;
    int s = rest % 3;
    int d = rest / 3;
    int b = n >> 7, t = n & 127;
    int pos = min(t + s, 127);
    int tok = (d == 0) ? S[b * 128 + pos] : S[b * 128 + 127 - pos];
    decX[flat] = emb[tok * 256 + k];
    if (k == 0) winTok[(d * 3 + s) * NN + n] = tok;
}

// ---------------- encoder step ----------------
// grid (32 slices of 8 units, 2 dirs), 256 threads
__global__ __launch_bounds__(256) void k_encstep(const int* __restrict__ S,
                                                 const float* __restrict__ emb,
                                                 const float* __restrict__ WencT,
                                                 const float* __restrict__ bih,
                                                 const float* __restrict__ bhh,
                                                 float* __restrict__ hEncS,
                                                 float* __restrict__ cEncS,
                                                 float* __restrict__ h0dec,
                                                 int t) {
    const int d = blockIdx.y;
    const int j0 = blockIdx.x * 8;
    const int tid = threadIdx.x;
    __shared__ float A[16][512];
    __shared__ float gl[16][32];
    const float* hprev = hEncS + (size_t)((t & 1) * 2 + d) * 16 * 256;
    float* hnext = hEncS + (size_t)(((t + 1) & 1) * 2 + d) * 16 * 256;
    // stage A = [h_prev | emb[tok]]
    #pragma unroll
    for (int l = 0; l < 32; ++l) {
        int idx = tid + l * 256;
        int b = idx >> 9, k = idx & 511;
        float v;
        if (k < 256) v = hprev[b * 256 + k];
        else {
            int tok = 0;
            if (t > 0) tok = (d == 0) ? S[b * 128 + t - 1] : S[b * 128 + 128 - t];
            v = emb[tok * 256 + (k - 256)];
        }
        A[b][k] = v;
    }
    __syncthreads();
    int rl = tid & 31;       // gate*8 + j
    int bq = tid >> 5;       // 0..7 -> batches bq, bq+8
    int gate = rl >> 3, jj = rl & 7;
    int r = gate * 256 + j0 + jj;
    float acc0 = bih[r] + bhh[r];
    float acc1 = acc0;
    const float* wp = WencT + r;
    #pragma unroll 4
    for (int k = 0; k < 512; ++k) {
        float w = wp[k * 1024];
        acc0 = fmaf(w, A[bq][k], acc0);
        acc1 = fmaf(w, A[bq + 8][k], acc1);
    }
    gl[bq][rl] = acc0;
    gl[bq + 8][rl] = acc1;
    __syncthreads();
    if (tid < 128) {
        int b = tid >> 3, j = tid & 7;
        int unit = j0 + j;
        float gi = gl[b][j], gf = gl[b][8 + j], gg = gl[b][16 + j], go = gl[b][24 + j];
        int ci = (d * 16 + b) * 256 + unit;
        float c = cEncS[ci];
        float cn = sigf(gf) * c + sigf(gi) * tanhsafe(gg);
        float h = sigf(go) * tanhsafe(cn);
        cEncS[ci] = cn;
        hnext[b * 256 + unit] = h;
        h0dec[((size_t)d * NN + b * 128 + t) * 256 + unit] = h;
    }
}

// ---------------- decoder GEMM (one dir per launch) ----------------
// g[n][r] = sum_k<256 Ah[n][k]*Whh[r][k] + sum Ax[n][k]*Wih[r][k] + bih[r]+bhh[r] (+xp0[r])
__global__ __launch_bounds__(256) void k_decgemm(const float* __restrict__ Ah,
                                                 const float* __restrict__ Ax,
                                                 const float* __restrict__ Whh,
                                                 const float* __restrict__ Wih,
                                                 const float* __restrict__ bih,
                                                 const float* __restrict__ bhh,
                                                 const float* __restrict__ xp0d,
                                                 float* __restrict__ gOut,
                                                 int nchunks) {
    __shared__ float a_s[64][17];
    __shared__ float b_s[16][65];
    int tid = threadIdx.x;
    int r0 = blockIdx.x * 64;
    int n0 = blockIdx.y * 64;
    int tx = tid & 15, ty = tid >> 4;
    float acc[4][4] = {{0.f}};
    for (int c = 0; c < nchunks; ++c) {
        int kk0 = c * 16;
        const float* Asrc = (kk0 < 256) ? Ah : Ax;
        const float* Wsrc = (kk0 < 256) ? Whh : Wih;
        int kof = (kk0 < 256) ? kk0 : (kk0 - 256);
        {
            int i = tid >> 2, k4 = (tid & 3) * 4;
            float4 v = *(const float4*)(Asrc + (size_t)(n0 + i) * 256 + kof + k4);
            a_s[i][k4] = v.x; a_s[i][k4 + 1] = v.y; a_s[i][k4 + 2] = v.z; a_s[i][k4 + 3] = v.w;
        }
        {
            int r_ = tid >> 2, k4 = (tid & 3) * 4;
            float4 v = *(const float4*)(Wsrc + (size_t)(r0 + r_) * 256 + kof + k4);
            b_s[k4][r_] = v.x; b_s[k4 + 1][r_] = v.y; b_s[k4 + 2][r_] = v.z; b_s[k4 + 3][r_] = v.w;
        }
        __syncthreads();
        #pragma unroll
        for (int kk = 0; kk < 16; ++kk) {
            float ar[4], br[4];
            #pragma unroll
            for (int i = 0; i < 4; ++i) ar[i] = a_s[ty * 4 + i][kk];
            #pragma unroll
            for (int j = 0; j < 4; ++j) br[j] = b_s[kk][tx * 4 + j];
            #pragma unroll
            for (int i = 0; i < 4; ++i)
                #pragma unroll
                for (int j = 0; j < 4; ++j) acc[i][j] = fmaf(ar[i], br[j], acc[i][j]);
        }
        __syncthreads();
    }
    #pragma unroll
    for (int i = 0; i < 4; ++i)
        #pragma unroll
        for (int j = 0; j < 4; ++j) {
            int r = r0 + tx * 4 + j;
            int n = n0 + ty * 4 + i;
            float g = acc[i][j] + bih[r] + bhh[r];
            if (xp0d) g += xp0d[r];
            gOut[(size_t)n * GG + r] = g;
        }
}

// ---------------- decoder cell ----------------
__global__ __launch_bounds__(256) void k_deccell(const float* __restrict__ gBuf,
                                                 const float* __restrict__ h0dec,
                                                 float* __restrict__ cDec,
                                                 float* __restrict__ hsAll,
                                                 int s) {
    int flat = blockIdx.x * 256 + threadIdx.x;  // 2*2048*256
    int j = flat & 255;
    int n = (flat >> 8) & 2047;
    int d = flat >> 19;
    const float* g = gBuf + (size_t)(d * NN + n) * GG;
    float gi = g[j], gf = g[j + 256], gg = g[j + 512], go = g[j + 768];
    float cprev = (s == 0) ? h0dec[flat] : cDec[flat];
    float cn = sigf(gf) * cprev + sigf(gi) * tanhsafe(gg);
    float h = sigf(go) * tanhsafe(cn);
    cDec[flat] = cn;
    hsAll[((size_t)(d * 4 + s) * NN) * 256 + (size_t)n * 256 + j] = h;
}

// ---------------- projection + online logsumexp + gather ----------------
// grid (64 n-tiles, 4 steps, 2 dirs), 256 threads; 32 rows x 128 col tile
__global__ __launch_bounds__(256) void k_proj(const float* __restrict__ hsAll,
                                              const float* __restrict__ Wpf,
                                              const float* __restrict__ Wpb,
                                              const float* __restrict__ bpf,
                                              const float* __restrict__ bpb,
                                              const int* __restrict__ winTok,
                                              float* __restrict__ logZ,
                                              float* __restrict__ gchar,
                                              float* __restrict__ gtag) {
    int d = blockIdx.z, s = blockIdx.y, n0 = blockIdx.x * 32;
    const float* Wp = d ? Wpb : Wpf;
    const float* bp = d ? bpb : bpf;
    const float* hs = hsAll + (size_t)(d * 4 + s) * NN * 256;
    __shared__ float a_s[32][257];
    __shared__ float b_s[16][129];
    int tid = threadIdx.x;
    int tx = tid & 31, ty = tid >> 5;
    // stage A rows (float4)
    #pragma unroll
    for (int l = 0; l < 8; ++l) {
        int f4 = tid + l * 256;          // 2048 float4s
        int i = f4 >> 6, k4 = (f4 & 63) * 4;
        float4 v = *(const float4*)(hs + (size_t)(n0 + i) * 256 + k4);
        a_s[i][k4] = v.x; a_s[i][k4 + 1] = v.y; a_s[i][k4 + 2] = v.z; a_s[i][k4 + 3] = v.w;
    }
    int tok[4];
    if (s < 3) {
        #pragma unroll
        for (int i = 0; i < 4; ++i) tok[i] = winTok[(d * 3 + s) * NN + n0 + ty * 4 + i];
    }
    float m[4], ssum[4];
    #pragma unroll
    for (int i = 0; i < 4; ++i) { m[i] = -1e30f; ssum[i] = 0.0f; }
    __syncthreads();
    for (int v0 = 0; v0 < VOCAB; v0 += 128) {
        float acc[4][4] = {{0.f}};
        for (int c = 0; c < 16; ++c) {
            #pragma unroll
            for (int l = 0; l < 2; ++l) {
                int f4 = tid + l * 256;              // 512 float4s = 2048 elems
                int v_ = f4 >> 2, k4 = (f4 & 3) * 4;
                int v = v0 + v_;
                float4 w;
                if (v < VOCAB) w = *(const float4*)(Wp + (size_t)v * 256 + c * 16 + k4);
                else { w.x = w.y = w.z = w.w = 0.0f; }
                b_s[k4][v_] = w.x; b_s[k4 + 1][v_] = w.y; b_s[k4 + 2][v_] = w.z; b_s[k4 + 3][v_] = w.w;
            }
            __syncthreads();
            #pragma unroll
            for (int kk = 0; kk < 16; ++kk) {
                float ar[4], br[4];
                #pragma unroll
                for (int i = 0; i < 4; ++i) ar[i] = a_s[ty * 4 + i][c * 16 + kk];
                #pragma unroll
                for (int j = 0; j < 4; ++j) br[j] = b_s[kk][tx * 4 + j];
                #pragma unroll
                for (int i = 0; i < 4; ++i)
                    #pragma unroll
                    for (int j = 0; j < 4; ++j) acc[i][j] = fmaf(ar[i], br[j], acc[i][j]);
            }
            __syncthreads();
        }
        // epilogue: bias, capture, online LSE
        #pragma unroll
        for (int i = 0; i < 4; ++i) {
            float lg[4];
            #pragma unroll
            for (int j = 0; j < 4; ++j) {
                int v = v0 + tx * 4 + j;
                if (v < VOCAB) {
                    float logit = acc[i][j] + bp[v];
                    lg[j] = logit;
                    int row = n0 + ty * 4 + i;
                    if (s < 3 && v == tok[i]) gchar[(d * 3 + s) * NN + row] = logit;
                    if (s >= 1 && v == 0) gtag[(d * 3 + (s - 1)) * NN + row] = logit;
                } else lg[j] = -1e30f;
            }
            float tmax = fmaxf(fmaxf(lg[0], lg[1]), fmaxf(lg[2], lg[3]));
            float mn = fmaxf(m[i], tmax);
            float add = 0.0f;
            #pragma unroll
            for (int j = 0; j < 4; ++j) add += (lg[j] > -1e29f) ? __expf(lg[j] - mn) : 0.0f;
            ssum[i] = ssum[i] * __expf(m[i] - mn) + add;
            m[i] = mn;
        }
    }
    // reduce across 32 tx lanes
    #pragma unroll
    for (int i = 0; i < 4; ++i) {
        float mi = m[i], si = ssum[i];
        for (int off = 16; off >= 1; off >>= 1) {
            float m2 = __shfl_xor(mi, off);
            float s2 = __shfl_xor(si, off);
            float M = fmaxf(mi, m2);
            si = si * __expf(mi - M) + s2 * __expf(m2 - M);
            mi = M;
        }
        if (tx == 0) logZ[(size_t)(d * 4 + s) * NN + n0 + ty * 4 + i] = mi + __logf(si);
    }
}

// ---------------- P assembly ----------------
__global__ __launch_bounds__(256) void k_passm(const float* __restrict__ gchar,
                                               const float* __restrict__ gtag,
                                               const float* __restrict__ logZ,
                                               float* __restrict__ P) {
    int flat = blockIdx.x * 256 + threadIdx.x;  // 128*3*16
    if (flat >= 128 * 3 * 16) return;
    int b = flat & 15;
    int y = (flat >> 4) % 3;
    int x = flat / 48;
    int nf = b * 128 + min(127, max(0, x - y));
    int nb = b * 128 + 127 - x;
    float pf = 0.0f, pb = 0.0f;
    for (int ss = 0; ss <= y; ++ss) {
        pf += gchar[ss * NN + nf] - logZ[ss * NN + nf];
        pb += gchar[(3 + ss) * NN + nb] - logZ[(4 + ss) * NN + nb];
    }
    pf += gtag[y * NN + nf] - logZ[(y + 1) * NN + nf];
    pb += gtag[(3 + y) * NN + nb] - logZ[(4 + y + 1) * NN + nb];
    P[flat] = 0.5f * (pf + pb);
}

// ---------------- semi-CRF scan + loss ----------------
__global__ __launch_bounds__(64) void k_scan(const float* __restrict__ P, float* __restrict__ out) {
    __shared__ float buf[3][16];
    __shared__ float cand[3][16];
    __shared__ float tot[16];
    int tid = threadIdx.x;
    if (tid < 48) buf[tid / 16][tid % 16] = 0.0f;
    __syncthreads();
    for (int j = 1; j <= 128; ++j) {
        if (tid < 48) {
            int i = tid / 16, b = tid % 16;
            cand[i][b] = (i < j) ? buf[i][b] + P[((j - 1) * 3 + i) * 16 + b] : -1e30f;
        }
        __syncthreads();
        if (tid < 16) {
            int b = tid;
            float c0 = cand[0][b], c1 = cand[1][b], c2 = cand[2][b];
            float mx = fmaxf(c0, fmaxf(c1, c2));
            float sv = __expf(c0 - mx) + __expf(c1 - mx) + __expf(c2 - mx);
            float t_ = mx + __logf(sv);
            float b0 = buf[0][b], b1 = buf[1][b];
            buf[0][b] = t_; buf[1][b] = b0; buf[2][b] = b1;
            tot[b] = t_;
        }
        __syncthreads();
    }
    if (tid == 0) {
        float s = 0.0f;
        for (int b = 0; b < 16; ++b) s += tot[b];
        out[0] = -s / 16.0f;
    }
}

// ---------------- launch ----------------
extern "C" void kernel_launch(void* const* d_in, const int* in_sizes, int n_in,
                              void* d_out, int out_size, void* d_ws, size_t ws_size,
                              hipStream_t stream) {
    const int* S = (const int*)d_in[0];
    const float* emb = (const float*)d_in[1];
    const float* eWih = (const float*)d_in[2];
    const float* eWhh = (const float*)d_in[3];
    const float* ebih = (const float*)d_in[4];
    const float* ebhh = (const float*)d_in[5];
    const float* fWih = (const float*)d_in[6];
    const float* fWhh = (const float*)d_in[7];
    const float* fbih = (const float*)d_in[8];
    const float* fbhh = (const float*)d_in[9];
    const float* fWp  = (const float*)d_in[10];
    const float* fbp  = (const float*)d_in[11];
    const float* bWih = (const float*)d_in[12];
    const float* bWhh = (const float*)d_in[13];
    const float* bbih = (const float*)d_in[14];
    const float* bbhh = (const float*)d_in[15];
    const float* bWp  = (const float*)d_in[16];
    const float* bbp  = (const float*)d_in[17];

    float* w = (float*)d_ws;
    float* WencT = w + OFF_WENCT;
    float* xp0   = w + OFF_XP0;
    float* hEncS = w + OFF_HENC;
    float* cEncS = w + OFF_CENC;
    float* h0dec = w + OFF_H0;
    float* decX  = w + OFF_DECX;
    float* cDec  = w + OFF_CDEC;
    float* hsAll = w + OFF_HS;
    float* gBuf  = w + OFF_GBUF;
    float* logZ  = w + OFF_LOGZ;
    float* gchar = w + OFF_GCH;
    float* gtag  = w + OFF_GTG;
    float* Pm    = w + OFF_P;
    int* winTok  = (int*)(w + OFF_WTOK);

    k_wenct<<<2048, 256, 0, stream>>>(eWhh, eWih, WencT);
    k_zero<<<96, 256, 0, stream>>>(hEncS, 16384 + 8192);  // hEncS + cEncS contiguous
    k_xp0<<<8, 256, 0, stream>>>(emb, fWih, bWih, xp0);
    k_decx<<<12288, 256, 0, stream>>>(S, emb, decX, winTok);

    for (int t = 0; t < 128; ++t)
        k_encstep<<<dim3(32, 2), 256, 0, stream>>>(S, emb, WencT, ebih, ebhh,
                                                   hEncS, cEncS, h0dec, t);

    const float* dWih[2] = {fWih, bWih};
    const float* dWhh[2] = {fWhh, bWhh};
    const float* dbih[2] = {fbih, bbih};
    const float* dbhh[2] = {fbhh, bbhh};
    for (int s = 0; s < 4; ++s) {
        for (int d = 0; d < 2; ++d) {
            const float* Ah = (s == 0) ? (h0dec + (size_t)d * NN * 256)
                                       : (hsAll + (size_t)(d * 4 + s - 1) * NN * 256);
            const float* Ax = (s == 0) ? nullptr
                                       : (decX + (size_t)(d * 3 + s - 1) * NN * 256);
            const float* xp = (s == 0) ? (xp0 + d * 1024) : nullptr;
            k_decgemm<<<dim3(16, 32), 256, 0, stream>>>(Ah, Ax, dWhh[d], dWih[d],
                                                        dbih[d], dbhh[d], xp,
                                                        gBuf + (size_t)d * NN * GG,
                                                        (s == 0) ? 16 : 32);
        }
        k_deccell<<<4096, 256, 0, stream>>>(gBuf, h0dec, cDec, hsAll, s);
    }

    k_proj<<<dim3(64, 4, 2), 256, 0, stream>>>(hsAll, fWp, bWp, fbp, bbp, winTok,
                                               logZ, gchar, gtag);
    k_passm<<<24, 256, 0, stream>>>(gchar, gtag, logZ, Pm);
    k_scan<<<1, 64, 0, stream>>>(Pm, (float*)d_out);
}

// Round 3
// 1330.222 us; speedup vs baseline: 4.8425x; 4.8425x over previous
//
#include <hip/hip_runtime.h>
#include <math.h>

#define VOCAB 8000
#define NN 2048   /* B*T */

typedef unsigned short u16;
typedef __attribute__((ext_vector_type(8))) short short8v;
typedef __attribute__((ext_vector_type(4))) short short4v;
typedef __attribute__((ext_vector_type(4))) float float4v;

// ---- workspace offsets (in float slots) ----
#define OFF_WPBF   0ul          /* bf16 [2][8000][256]      2,048,000 */
#define OFF_WDEC   2048000ul    /* bf16 [2][1024][512]        524,288 */
#define OFF_XENC   2572288ul    /* bf16 [2][128][16][256]     524,288 */
#define OFF_HENCBF 3096576ul    /* bf16 [2par][2d][16][256]     8,192 */
#define OFF_H0DEC  3104768ul    /* f32  [2][2048][256]      1,048,576 */
#define OFF_H0BF   4153344ul    /* bf16 [2][2048][256]        524,288 */
#define OFF_DECX   4677632ul    /* bf16 [2][3][2048][256]   1,572,864 */
#define OFF_CDEC   6250496ul    /* f32  [2][2048][256]      1,048,576 */
#define OFF_HSBF   7299072ul    /* bf16 [8][2048][256]      2,097,152 */
#define OFF_GBUF   9396224ul    /* f32  [2][2048][1024]     4,194,304  (aliased: partials [8][2048][126]) */
#define OFF_LOGZ   13590528ul   /* f32  [8][2048]              16,384 */
#define OFF_GCH    13606912ul   /* f32  [2][3][2048]           12,288 */
#define OFF_GTG    13619200ul   /* f32  [2][3][2048]           12,288 */
#define OFF_P      13631488ul   /* f32  [128][3][16]            6,144 */
#define OFF_WTOK   13637632ul   /* int  [2][3][2048]           12,288 */
#define OFF_XP0    13649920ul   /* f32  [2][1024]               2,048 */
#define OFF_BAR    13651968ul   /* int  barrier                    64 */

__device__ __forceinline__ float sigf(float x) { return 1.0f / (1.0f + __expf(-x)); }
__device__ __forceinline__ float tanhsafe(float x) {
    x = fminf(15.0f, fmaxf(-15.0f, x));
    float e = __expf(2.0f * x);
    return (e - 1.0f) / (e + 1.0f);
}
__device__ __forceinline__ u16 f2bf(float f) {
    union { float f; unsigned int u; } x; x.f = f;
    return (u16)((x.u + 0x7fffu + ((x.u >> 16) & 1u)) >> 16);
}

// MFMA fragment load from a swizzled LDS tile. Rows of SB bytes; lane l reads
// row (row + (l&15)), 8 contiguous bf16 at k + (l>>4)*8. XOR swizzle (r&7)<<4.
__device__ __forceinline__ short8v ldfrag(const u16* lds, int row, int k, int lane, int SB) {
    int r = row + (lane & 15);
    int off = r * SB + ((k + ((lane >> 4) << 3)) << 1);
    off ^= (r & 7) << 4;
    return *(const short8v*)((const char*)lds + off);
}

// Stage a 128x256 bf16 tile (row-major, rowstride elems) into swizzled LDS.
__device__ __forceinline__ void stage128x256(const u16* __restrict__ g, int row0, int rowmax,
                                             int rowstride, int col0, u16* lds, int tid) {
    #pragma unroll
    for (int it = 0; it < 16; ++it) {
        int chunk = tid + it * 256;
        int r = chunk >> 5;
        int kc = (chunk & 31) << 3;
        short8v v = {0, 0, 0, 0, 0, 0, 0, 0};
        if (row0 + r < rowmax)
            v = *(const short8v*)(g + (size_t)(row0 + r) * rowstride + col0 + kc);
        int off = (r * 512 + kc * 2) ^ ((r & 7) << 4);
        *(short8v*)((char*)lds + off) = v;
    }
}

// ---------------- setup kernels ----------------

__global__ __launch_bounds__(256) void k_zero(float* __restrict__ p, int n) {
    int i = blockIdx.x * 256 + threadIdx.x;
    if (i < n) p[i] = 0.0f;
}

__global__ __launch_bounds__(256) void k_wpbf(const float* __restrict__ Wf,
                                              const float* __restrict__ Wb,
                                              u16* __restrict__ out) {
    int chunk = blockIdx.x * 256 + threadIdx.x;   // 2*8000*32 = 512000
    int kc = (chunk & 31) << 3;
    int v = (chunk >> 5) % 8000;
    int d = chunk / (8000 * 32);
    const float* src = (d ? Wb : Wf) + (size_t)v * 256 + kc;
    u16 t8[8];
    #pragma unroll
    for (int j = 0; j < 8; ++j) t8[j] = f2bf(src[j]);
    *(short8v*)(out + ((size_t)d * 8000 + v) * 256 + kc) = *(short8v*)t8;
}

// WdecBF[d][r][k]: k<256 -> Whh[r][k], else Wih[r][k-256]
__global__ __launch_bounds__(256) void k_wdecbf(const float* __restrict__ fWhh, const float* __restrict__ fWih,
                                                const float* __restrict__ bWhh, const float* __restrict__ bWih,
                                                u16* __restrict__ out) {
    int chunk = blockIdx.x * 256 + threadIdx.x;   // 2*1024*64 = 131072
    int kc = (chunk & 63) << 3;
    int r = (chunk >> 6) & 1023;
    int d = chunk >> 16;
    const float* Whh = d ? bWhh : fWhh;
    const float* Wih = d ? bWih : fWih;
    const float* src = (kc < 256) ? (Whh + (size_t)r * 256 + kc) : (Wih + (size_t)r * 256 + (kc - 256));
    u16 t8[8];
    #pragma unroll
    for (int j = 0; j < 8; ++j) t8[j] = f2bf(src[j]);
    *(short8v*)(out + ((size_t)d * 1024 + r) * 512 + kc) = *(short8v*)t8;
}

// xEncBF[d][t][b][k] = bf16(emb[tok]), tok = t==0 ? 0 : (fwd S[b][t-1] / bwd S[b][128-t])
__global__ __launch_bounds__(256) void k_xenc(const int* __restrict__ S, const float* __restrict__ emb,
                                              u16* __restrict__ out) {
    int chunk = blockIdx.x * 256 + threadIdx.x;   // 2*128*16*32 = 131072
    int kc = (chunk & 31) << 3;
    int b = (chunk >> 5) & 15;
    int t = (chunk >> 9) & 127;
    int d = chunk >> 16;
    int tok = 0;
    if (t > 0) tok = d ? S[b * 128 + 128 - t] : S[b * 128 + t - 1];
    const float* src = emb + (size_t)tok * 256 + kc;
    u16 t8[8];
    #pragma unroll
    for (int j = 0; j < 8; ++j) t8[j] = f2bf(src[j]);
    *(short8v*)(out + (size_t)(((d * 128 + t) * 16) + b) * 256 + kc) = *(short8v*)t8;
}

__global__ __launch_bounds__(256) void k_decx(const int* __restrict__ S, const float* __restrict__ emb,
                                              u16* __restrict__ decX, int* __restrict__ winTok) {
    int chunk = blockIdx.x * 256 + threadIdx.x;   // 2*3*2048*32 = 393216
    int kc = (chunk & 31) << 3;
    int n = (chunk >> 5) & 2047;
    int r2 = chunk >> 16;
    int s = r2 % 3, d = r2 / 3;
    int b = n >> 7, tq = n & 127;
    int pos = min(tq + s, 127);
    int tok = d ? S[b * 128 + 127 - pos] : S[b * 128 + pos];
    const float* src = emb + (size_t)tok * 256 + kc;
    u16 t8[8];
    #pragma unroll
    for (int j = 0; j < 8; ++j) t8[j] = f2bf(src[j]);
    *(short8v*)(decX + ((size_t)(d * 3 + s) * NN + n) * 256 + kc) = *(short8v*)t8;
    if ((chunk & 31) == 0) winTok[(d * 3 + s) * NN + n] = tok;
}

// xp0[d][r] = emb[PART=0] . Wih_d[r]  (f32, exact)
__global__ __launch_bounds__(256) void k_xp0(const float* __restrict__ emb,
                                             const float* __restrict__ Wihf,
                                             const float* __restrict__ Wihb,
                                             float* __restrict__ xp0) {
    int idx = blockIdx.x * 256 + threadIdx.x;  // 2048
    int d = idx >> 10, r = idx & 1023;
    const float* Wih = d ? Wihb : Wihf;
    float acc = 0.0f;
    for (int k = 0; k < 256; ++k) acc = fmaf(emb[k], Wih[r * 256 + k], acc);
    xp0[idx] = acc;
}

// ---------------- persistent encoder (32 blocks, grid barrier) ----------------
__global__ __launch_bounds__(256) void k_enc(const float* __restrict__ eWih,
                                             const float* __restrict__ eWhh,
                                             const float* __restrict__ ebih,
                                             const float* __restrict__ ebhh,
                                             const u16* __restrict__ xEnc,
                                             u16* __restrict__ hEncBF,
                                             float* __restrict__ h0dec,
                                             u16* __restrict__ h0bf,
                                             int* __restrict__ bar) {
    __shared__ u16 Wl[64 * 512];     // 64 rows (gate*16+jj) x 512 k, swizzled, 64KB
    __shared__ u16 Ax[16 * 512];     // 16 b x [h|x] 512 k, swizzled, 16KB
    __shared__ float gl[16 * 64];
    __shared__ u16 hx[256];
    const int tid = threadIdx.x;
    const int lane = tid & 63;
    const int wid = tid >> 6;
    const int d = blockIdx.x >> 4;
    const int j0 = (blockIdx.x & 15) << 4;

    // one-time weight stage: row rr=g*16+jj <- r_g = g*256+j0+jj
    {
        int rr = tid >> 2, q = tid & 3;
        int rg = ((rr >> 4) << 8) + j0 + (rr & 15);
        for (int kk = 0; kk < 32; ++kk) {
            int k = q * 128 + kk * 4;
            const float* s4 = (k < 256) ? (eWhh + (size_t)rg * 256 + k)
                                        : (eWih + (size_t)rg * 256 + (k - 256));
            float4 v = *(const float4*)s4;
            u16 t4[4] = {f2bf(v.x), f2bf(v.y), f2bf(v.z), f2bf(v.w)};
            int off = (rr * 1024 + k * 2) ^ ((rr & 7) << 4);
            *(short4v*)((char*)Wl + off) = *(short4v*)t4;
        }
    }
    const int cb = tid >> 4, cj = tid & 15;
    const float bI = ebih[j0 + cj] + ebhh[j0 + cj];
    const float bF = ebih[256 + j0 + cj] + ebhh[256 + j0 + cj];
    const float bG = ebih[512 + j0 + cj] + ebhh[512 + j0 + cj];
    const float bO = ebih[768 + j0 + cj] + ebhh[768 + j0 + cj];
    float creg = 0.0f;
    __syncthreads();

    for (int t = 0; t < 128; ++t) {
        int par = t & 1;
        // stage h: 16 batches x 256 units = 8192 B -> 4 loops x 256 thr x 8 B
        const unsigned long long* hsrc =
            (const unsigned long long*)(hEncBF + (size_t)(par * 2 + d) * 4096);
        #pragma unroll
        for (int l = 0; l < 4; ++l) {
            int i = tid + l * 256;  // 1024 x 8B
            unsigned long long v = __hip_atomic_load(&hsrc[i], __ATOMIC_RELAXED, __HIP_MEMORY_SCOPE_AGENT);
            int e = i << 2;
            int b = e >> 8, k = e & 255;
            int off = (b * 1024 + k * 2) ^ ((b & 7) << 4);
            *(unsigned long long*)((char*)Ax + off) = v;
        }
        // stage x: 16 batches x 256 = 8192 B -> 2 loops x 256 thr x 16 B
        const u16* xsrc = xEnc + (size_t)((d * 128 + t) * 16) * 256;
        #pragma unroll
        for (int l = 0; l < 2; ++l) {
            int i = tid + l * 256;  // 512 x 16B
            int e = i << 3;
            int b = e >> 8, k = e & 255;
            short8v v = *(const short8v*)(xsrc + e);
            int off = (b * 1024 + (256 + k) * 2) ^ ((b & 7) << 4);
            *(short8v*)((char*)Ax + off) = v;
        }
        __syncthreads();
        // wave `wid` computes gate `wid` for 16 units x 16 batches
        float4v acc = {0.f, 0.f, 0.f, 0.f};
        #pragma unroll
        for (int ks = 0; ks < 16; ++ks) {
            short8v af = ldfrag(Ax, 0, ks * 32, lane, 1024);
            short8v bf = ldfrag(Wl, wid * 16, ks * 32, lane, 1024);
            acc = __builtin_amdgcn_mfma_f32_16x16x32_bf16(af, bf, acc, 0, 0, 0);
        }
        #pragma unroll
        for (int i = 0; i < 4; ++i)
            gl[((((lane >> 4) << 2) + i) << 6) + (wid << 4) + (lane & 15)] = acc[i];
        __syncthreads();
        // cell (c stays in registers)
        {
            float gi = gl[(cb << 6) + cj] + bI;
            float gf = gl[(cb << 6) + 16 + cj] + bF;
            float gg = gl[(cb << 6) + 32 + cj] + bG;
            float go = gl[(cb << 6) + 48 + cj] + bO;
            float cn = sigf(gf) * creg + sigf(gi) * tanhsafe(gg);
            float h = sigf(go) * tanhsafe(cn);
            creg = cn;
            size_t ni = (size_t)d * NN + cb * 128 + t;
            h0dec[ni * 256 + j0 + cj] = h;
            h0bf[ni * 256 + j0 + cj] = f2bf(h);
            hx[(cb << 4) + cj] = f2bf(h);
        }
        __syncthreads();
        if (tid < 128) {
            int b = tid >> 3, p = tid & 7;
            unsigned int lo = hx[(b << 4) + 2 * p], hi = hx[(b << 4) + 2 * p + 1];
            unsigned int val = lo | (hi << 16);
            unsigned int* hdst = (unsigned int*)(hEncBF + (size_t)(((par ^ 1) * 2 + d) * 4096));
            __hip_atomic_store(&hdst[b * 128 + (j0 >> 1) + p], val, __ATOMIC_RELAXED, __HIP_MEMORY_SCOPE_AGENT);
        }
        __syncthreads();   // drains stores before the counter add
        if (tid == 0) {
            __hip_atomic_fetch_add(bar, 1, __ATOMIC_ACQ_REL, __HIP_MEMORY_SCOPE_AGENT);
            int target = 32 * (t + 1);
            while (__hip_atomic_load(bar, __ATOMIC_ACQUIRE, __HIP_MEMORY_SCOPE_AGENT) < target)
                __builtin_amdgcn_s_sleep(1);
        }
        __syncthreads();
    }
}

// ---------------- decoder gate GEMM (MFMA, 128x128 tile, K phases) ----------------
__global__ __launch_bounds__(256) void k_decmm(const u16* __restrict__ Ah, size_t ahStride,
                                               const u16* __restrict__ Axx, size_t axStride,
                                               const u16* __restrict__ Wdec,
                                               const float* __restrict__ bihf, const float* __restrict__ bhhf,
                                               const float* __restrict__ bihb, const float* __restrict__ bhhb,
                                               const float* __restrict__ xp0, int useX,
                                               float* __restrict__ gBuf) {
    __shared__ u16 At[128 * 256];
    __shared__ u16 Bt[128 * 256];
    const int tid = threadIdx.x, lane = tid & 63, wid = tid >> 6;
    const int wm = wid >> 1, wv = wid & 1;
    const int r0 = blockIdx.x * 128, n0 = blockIdx.y * 128, d = blockIdx.z;
    float4v acc[4][4];
    #pragma unroll
    for (int m = 0; m < 4; ++m)
        #pragma unroll
        for (int v = 0; v < 4; ++v) acc[m][v] = (float4v){0.f, 0.f, 0.f, 0.f};
    const int nph = useX ? 2 : 1;
    for (int ph = 0; ph < nph; ++ph) {
        const u16* Asrc = (ph == 0) ? (Ah + (size_t)d * ahStride) : (Axx + (size_t)d * axStride);
        stage128x256(Asrc, n0, 1 << 30, 256, 0, At, tid);
        stage128x256(Wdec + (size_t)d * 1024 * 512, r0, 1 << 30, 512, ph * 256, Bt, tid);
        __syncthreads();
        #pragma unroll
        for (int k = 0; k < 8; ++k) {
            short8v af[4], bf[4];
            #pragma unroll
            for (int m = 0; m < 4; ++m) af[m] = ldfrag(At, wm * 64 + m * 16, k * 32, lane, 512);
            #pragma unroll
            for (int v = 0; v < 4; ++v) bf[v] = ldfrag(Bt, wv * 64 + v * 16, k * 32, lane, 512);
            #pragma unroll
            for (int m = 0; m < 4; ++m)
                #pragma unroll
                for (int v = 0; v < 4; ++v)
                    acc[m][v] = __builtin_amdgcn_mfma_f32_16x16x32_bf16(af[m], bf[v], acc[m][v], 0, 0, 0);
        }
        __syncthreads();
    }
    const float* bih = d ? bihb : bihf;
    const float* bhh = d ? bhhb : bhhf;
    float bs[4]; int rg[4];
    #pragma unroll
    for (int v = 0; v < 4; ++v) {
        rg[v] = r0 + wv * 64 + v * 16 + (lane & 15);
        bs[v] = bih[rg[v]] + bhh[rg[v]];
        if (!useX) bs[v] += xp0[d * 1024 + rg[v]];
    }
    #pragma unroll
    for (int m = 0; m < 4; ++m)
        #pragma unroll
        for (int i = 0; i < 4; ++i) {
            int n = n0 + wm * 64 + m * 16 + ((lane >> 4) << 2) + i;
            #pragma unroll
            for (int v = 0; v < 4; ++v)
                gBuf[((size_t)d * NN + n) * 1024 + rg[v]] = acc[m][v][i] + bs[v];
        }
}

// ---------------- decoder cell ----------------
__global__ __launch_bounds__(256) void k_deccell(const float* __restrict__ gBuf,
                                                 const float* __restrict__ h0dec,
                                                 float* __restrict__ cDec,
                                                 u16* __restrict__ hsBF, int s) {
    int flat = blockIdx.x * 256 + threadIdx.x;  // 2*2048*256
    int j = flat & 255;
    int n = (flat >> 8) & 2047;
    int d = flat >> 19;
    const float* g = gBuf + ((size_t)d * NN + n) * 1024;
    float gi = g[j], gf = g[j + 256], gg = g[j + 512], go = g[j + 768];
    float cprev = (s == 0) ? h0dec[flat] : cDec[flat];
    float cn = sigf(gf) * cprev + sigf(gi) * tanhsafe(gg);
    float h = sigf(go) * tanhsafe(cn);
    cDec[flat] = cn;
    hsBF[((size_t)(d * 4 + s) * NN + n) * 256 + j] = f2bf(h);
}

// ---------------- projection MFMA + fused online LSE + gathers ----------------
__global__ __launch_bounds__(256) void k_proj(const u16* __restrict__ hsBF,
                                              const u16* __restrict__ WpBF,
                                              const float* __restrict__ bpf, const float* __restrict__ bpb,
                                              const int* __restrict__ winTok,
                                              float* __restrict__ partials,
                                              float* __restrict__ gchar, float* __restrict__ gtag) {
    __shared__ u16 At[128 * 256];
    __shared__ u16 Bt[128 * 256];
    const int tid = threadIdx.x, lane = tid & 63, wid = tid >> 6;
    const int wm = wid >> 1, wv = wid & 1;
    const int vt = blockIdx.x, n0 = blockIdx.y * 128, z = blockIdx.z;
    const int d = z >> 2, s = z & 3;
    const int v0 = vt * 128;
    const float* bp = d ? bpb : bpf;
    stage128x256(hsBF + (size_t)z * NN * 256, n0, 1 << 30, 256, 0, At, tid);
    stage128x256(WpBF + (size_t)d * 8000 * 256, v0, 8000, 256, 0, Bt, tid);
    __syncthreads();
    float4v acc[4][4];
    #pragma unroll
    for (int m = 0; m < 4; ++m)
        #pragma unroll
        for (int v = 0; v < 4; ++v) acc[m][v] = (float4v){0.f, 0.f, 0.f, 0.f};
    #pragma unroll
    for (int k = 0; k < 8; ++k) {
        short8v af[4], bf[4];
        #pragma unroll
        for (int m = 0; m < 4; ++m) af[m] = ldfrag(At, wm * 64 + m * 16, k * 32, lane, 512);
        #pragma unroll
        for (int v = 0; v < 4; ++v) bf[v] = ldfrag(Bt, wv * 64 + v * 16, k * 32, lane, 512);
        #pragma unroll
        for (int m = 0; m < 4; ++m)
            #pragma unroll
            for (int v = 0; v < 4; ++v)
                acc[m][v] = __builtin_amdgcn_mfma_f32_16x16x32_bf16(af[m], bf[v], acc[m][v], 0, 0, 0);
    }
    // epilogue: bias, capture char/tag, per-row LSE over this 64-col half
    float bpv[4]; int vg[4];
    #pragma unroll
    for (int v = 0; v < 4; ++v) {
        vg[v] = v0 + wv * 64 + v * 16 + (lane & 15);
        bpv[v] = (vg[v] < VOCAB) ? bp[vg[v]] : 0.0f;
    }
    #pragma unroll
    for (int m = 0; m < 4; ++m)
        #pragma unroll
        for (int i = 0; i < 4; ++i) {
            int n = n0 + wm * 64 + m * 16 + ((lane >> 4) << 2) + i;
            int tok = (s < 3) ? winTok[(d * 3 + s) * NN + n] : -1;
            float lgs[4];
            float mx = -1e30f;
            #pragma unroll
            for (int v = 0; v < 4; ++v) {
                float lg = (vg[v] < VOCAB) ? acc[m][v][i] + bpv[v] : -1e30f;
                lgs[v] = lg;
                mx = fmaxf(mx, lg);
                if (vg[v] == tok) gchar[(d * 3 + s) * NN + n] = lg;
                if (s >= 1 && vg[v] == 0) gtag[(d * 3 + (s - 1)) * NN + n] = lg;
            }
            float sum = 0.0f;
            #pragma unroll
            for (int v = 0; v < 4; ++v) sum += __expf(lgs[v] - mx);
            #pragma unroll
            for (int off = 1; off <= 8; off <<= 1) {
                float m2 = __shfl_xor(mx, off);
                float s2 = __shfl_xor(sum, off);
                float M = fmaxf(mx, m2);
                sum = sum * __expf(mx - M) + s2 * __expf(m2 - M);
                mx = M;
            }
            if ((lane & 15) == 0)
                partials[((size_t)z * NN + n) * 126 + vt * 2 + wv] = mx + __logf(sum);
        }
}

// ---------------- LSE reduce over 126 v-halves ----------------
__global__ __launch_bounds__(256) void k_lzred(const float* __restrict__ partials,
                                               float* __restrict__ logZ) {
    int wid = threadIdx.x >> 6, lane = threadIdx.x & 63;
    int row = blockIdx.x * 4 + wid;  // 0..16383
    const float* p = partials + (size_t)row * 126;
    float mx = p[lane];
    float sum = 1.0f;
    if (lane + 64 < 126) {
        float b = p[lane + 64];
        float M = fmaxf(mx, b);
        sum = __expf(mx - M) + __expf(b - M);
        mx = M;
    }
    #pragma unroll
    for (int off = 1; off <= 32; off <<= 1) {
        float m2 = __shfl_xor(mx, off);
        float s2 = __shfl_xor(sum, off);
        float M = fmaxf(mx, m2);
        sum = sum * __expf(mx - M) + s2 * __expf(m2 - M);
        mx = M;
    }
    if (lane == 0) logZ[row] = mx + __logf(sum);
}

// ---------------- P assembly ----------------
__global__ __launch_bounds__(256) void k_passm(const float* __restrict__ gchar,
                                               const float* __restrict__ gtag,
                                               const float* __restrict__ logZ,
                                               float* __restrict__ P) {
    int flat = blockIdx.x * 256 + threadIdx.x;  // 128*3*16
    if (flat >= 128 * 3 * 16) return;
    int b = flat & 15;
    int y = (flat >> 4) % 3;
    int x = flat / 48;
    int nf = b * 128 + min(127, max(0, x - y));
    int nb = b * 128 + 127 - x;
    float pf = 0.0f, pb = 0.0f;
    for (int ss = 0; ss <= y; ++ss) {
        pf += gchar[ss * NN + nf] - logZ[ss * NN + nf];
        pb += gchar[(3 + ss) * NN + nb] - logZ[(4 + ss) * NN + nb];
    }
    pf += gtag[y * NN + nf] - logZ[(y + 1) * NN + nf];
    pb += gtag[(3 + y) * NN + nb] - logZ[(4 + y + 1) * NN + nb];
    P[flat] = 0.5f * (pf + pb);
}

// ---------------- semi-CRF scan + loss ----------------
__global__ __launch_bounds__(64) void k_scan(const float* __restrict__ P, float* __restrict__ out) {
    __shared__ float buf[3][16];
    __shared__ float cand[3][16];
    __shared__ float tot[16];
    int tid = threadIdx.x;
    if (tid < 48) buf[tid / 16][tid % 16] = 0.0f;
    __syncthreads();
    for (int j = 1; j <= 128; ++j) {
        if (tid < 48) {
            int i = tid / 16, b = tid % 16;
            cand[i][b] = (i < j) ? buf[i][b] + P[((j - 1) * 3 + i) * 16 + b] : -1e30f;
        }
        __syncthreads();
        if (tid < 16) {
            int b = tid;
            float c0 = cand[0][b], c1 = cand[1][b], c2 = cand[2][b];
            float mx = fmaxf(c0, fmaxf(c1, c2));
            float sv = __expf(c0 - mx) + __expf(c1 - mx) + __expf(c2 - mx);
            float t_ = mx + __logf(sv);
            float b0 = buf[0][b], b1 = buf[1][b];
            buf[0][b] = t_; buf[1][b] = b0; buf[2][b] = b1;
            tot[b] = t_;
        }
        __syncthreads();
    }
    if (tid == 0) {
        float sacc = 0.0f;
        for (int b = 0; b < 16; ++b) sacc += tot[b];
        out[0] = -sacc / 16.0f;
    }
}

// ---------------- launch ----------------
extern "C" void kernel_launch(void* const* d_in, const int* in_sizes, int n_in,
                              void* d_out, int out_size, void* d_ws, size_t ws_size,
                              hipStream_t stream) {
    const int* S = (const int*)d_in[0];
    const float* emb = (const float*)d_in[1];
    const float* eWih = (const float*)d_in[2];
    const float* eWhh = (const float*)d_in[3];
    const float* ebih = (const float*)d_in[4];
    const float* ebhh = (const float*)d_in[5];
    const float* fWih = (const float*)d_in[6];
    const float* fWhh = (const float*)d_in[7];
    const float* fbih = (const float*)d_in[8];
    const float* fbhh = (const float*)d_in[9];
    const float* fWp  = (const float*)d_in[10];
    const float* fbp  = (const float*)d_in[11];
    const float* bWih = (const float*)d_in[12];
    const float* bWhh = (const float*)d_in[13];
    const float* bbih = (const float*)d_in[14];
    const float* bbhh = (const float*)d_in[15];
    const float* bWp  = (const float*)d_in[16];
    const float* bbp  = (const float*)d_in[17];

    float* w = (float*)d_ws;
    u16* WpBF    = (u16*)(w + OFF_WPBF);
    u16* WdecBF  = (u16*)(w + OFF_WDEC);
    u16* xEncBF  = (u16*)(w + OFF_XENC);
    u16* hEncBF  = (u16*)(w + OFF_HENCBF);
    float* h0dec = w + OFF_H0DEC;
    u16* h0bf    = (u16*)(w + OFF_H0BF);
    u16* decXBF  = (u16*)(w + OFF_DECX);
    float* cDec  = w + OFF_CDEC;
    u16* hsBF    = (u16*)(w + OFF_HSBF);
    float* gBuf  = w + OFF_GBUF;
    float* partials = gBuf;   // aliased: decoder done before projection
    float* logZ  = w + OFF_LOGZ;
    float* gchar = w + OFF_GCH;
    float* gtag  = w + OFF_GTG;
    float* Pm    = w + OFF_P;
    int* winTok  = (int*)(w + OFF_WTOK);
    float* xp0   = w + OFF_XP0;
    int* bar     = (int*)(w + OFF_BAR);

    k_zero<<<32, 256, 0, stream>>>(w + OFF_HENCBF, 8192);
    k_zero<<<1, 256, 0, stream>>>(w + OFF_BAR, 64);
    k_wpbf<<<2000, 256, 0, stream>>>(fWp, bWp, WpBF);
    k_wdecbf<<<512, 256, 0, stream>>>(fWhh, fWih, bWhh, bWih, WdecBF);
    k_xenc<<<512, 256, 0, stream>>>(S, emb, xEncBF);
    k_decx<<<1536, 256, 0, stream>>>(S, emb, decXBF, winTok);
    k_xp0<<<8, 256, 0, stream>>>(emb, fWih, bWih, xp0);

    k_enc<<<32, 256, 0, stream>>>(eWih, eWhh, ebih, ebhh, xEncBF, hEncBF, h0dec, h0bf, bar);

    for (int s = 0; s < 4; ++s) {
        const u16* Ah; size_t ahS;
        const u16* Axx; size_t axS;
        if (s == 0) {
            Ah = h0bf; ahS = (size_t)NN * 256;
            Axx = decXBF; axS = (size_t)3 * NN * 256;  // unused
        } else {
            Ah = hsBF + (size_t)(s - 1) * NN * 256; ahS = (size_t)4 * NN * 256;
            Axx = decXBF + (size_t)(s - 1) * NN * 256; axS = (size_t)3 * NN * 256;
        }
        k_decmm<<<dim3(8, 16, 2), 256, 0, stream>>>(Ah, ahS, Axx, axS, WdecBF,
                                                    fbih, fbhh, bbih, bbhh, xp0,
                                                    (s == 0) ? 0 : 1, gBuf);
        k_deccell<<<4096, 256, 0, stream>>>(gBuf, h0dec, cDec, hsBF, s);
    }

    k_proj<<<dim3(63, 16, 8), 256, 0, stream>>>(hsBF, WpBF, fbp, bbp, winTok,
                                                partials, gchar, gtag);
    k_lzred<<<4096, 256, 0, stream>>>(partials, logZ);
    k_passm<<<24, 256, 0, stream>>>(gchar, gtag, logZ, Pm);
    k_scan<<<1, 64, 0, stream>>>(Pm, (float*)d_out);
}

// Round 4
// 977.358 us; speedup vs baseline: 6.5908x; 1.3610x over previous
//
#include <hip/hip_runtime.h>
#include <math.h>

#define VOCAB 8000
#define NN 2048   /* B*T */

typedef unsigned short u16;
typedef __attribute__((ext_vector_type(8))) short short8v;
typedef __attribute__((ext_vector_type(4))) short short4v;
typedef __attribute__((ext_vector_type(4))) float float4v;

// ---- workspace offsets (in float slots) ----
#define OFF_WPBF   0ul          /* bf16 [2][8000][256]      2,048,000 */
#define OFF_WDEC   2048000ul    /* bf16 [2][1024][512]        524,288 */
#define OFF_XENC   2572288ul    /* bf16 [2][128][16][256]     524,288 */
#define OFF_HENCBF 3096576ul    /* bf16 [2par][2d][16][256]     8,192 */
#define OFF_H0DEC  3104768ul    /* f32  [2][2048][256]      1,048,576 */
#define OFF_H0BF   4153344ul    /* bf16 [2][2048][256]        524,288 */
#define OFF_DECX   4677632ul    /* bf16 [2][3][2048][256]   1,572,864 */
#define OFF_CDEC   6250496ul    /* f32  [2][2048][256]      1,048,576 */
#define OFF_HSBF   7299072ul    /* bf16 [8][2048][256]      2,097,152 */
#define OFF_GBUF   9396224ul    /* f32  [2][2048][1024]     4,194,304 (aliased: xprojb, then partials) */
#define OFF_LOGZ   13590528ul   /* f32  [8][2048]              16,384 */
#define OFF_GCH    13606912ul   /* f32  [2][3][2048]           12,288 */
#define OFF_GTG    13619200ul   /* f32  [2][3][2048]           12,288 */
#define OFF_P      13631488ul   /* f32  [128][3][16]            6,144 */
#define OFF_WTOK   13637632ul   /* int  [2][3][2048]           12,288 */
#define OFF_XP0    13649920ul   /* f32  [2][1024]               2,048 */
#define OFF_BAR    13651968ul   /* int  barrier (unused now)       64 */
#define OFF_ENCW   13652032ul   /* bf16 [1024][512]           262,144 */
#define OFF_FLAGS  13914176ul   /* int  [8*32]                    256 */

__device__ __forceinline__ float sigf(float x) { return 1.0f / (1.0f + __expf(-x)); }
__device__ __forceinline__ float tanhsafe(float x) {
    x = fminf(15.0f, fmaxf(-15.0f, x));
    float e = __expf(2.0f * x);
    return (e - 1.0f) / (e + 1.0f);
}
__device__ __forceinline__ u16 f2bf(float f) {
    union { float f; unsigned int u; } x; x.f = f;
    return (u16)((x.u + 0x7fffu + ((x.u >> 16) & 1u)) >> 16);
}

// MFMA fragment load from a swizzled LDS tile. Rows of SB bytes; lane l reads
// row (row + (l&15)), 8 contiguous bf16 at k + (l>>4)*8. XOR swizzle (r&7)<<4.
__device__ __forceinline__ short8v ldfrag(const u16* lds, int row, int k, int lane, int SB) {
    int r = row + (lane & 15);
    int off = r * SB + ((k + ((lane >> 4) << 3)) << 1);
    off ^= (r & 7) << 4;
    return *(const short8v*)((const char*)lds + off);
}

// Stage a 128x256 bf16 tile (row-major, rowstride elems) into swizzled LDS (rowbytes 512).
__device__ __forceinline__ void stage128x256(const u16* __restrict__ g, int row0, int rowmax,
                                             int rowstride, int col0, u16* lds, int tid) {
    #pragma unroll
    for (int it = 0; it < 16; ++it) {
        int chunk = tid + it * 256;
        int r = chunk >> 5;
        int kc = (chunk & 31) << 3;
        short8v v = {0, 0, 0, 0, 0, 0, 0, 0};
        if (row0 + r < rowmax)
            v = *(const short8v*)(g + (size_t)(row0 + r) * rowstride + col0 + kc);
        int off = (r * 512 + kc * 2) ^ ((r & 7) << 4);
        *(short8v*)((char*)lds + off) = v;
    }
}

// ---------------- setup kernels ----------------

__global__ __launch_bounds__(256) void k_zero(float* __restrict__ p, int n) {
    int i = blockIdx.x * 256 + threadIdx.x;
    if (i < n) p[i] = 0.0f;
}

__global__ __launch_bounds__(256) void k_wpbf(const float* __restrict__ Wf,
                                              const float* __restrict__ Wb,
                                              u16* __restrict__ out) {
    int chunk = blockIdx.x * 256 + threadIdx.x;   // 2*8000*32 = 512000
    int kc = (chunk & 31) << 3;
    int v = (chunk >> 5) % 8000;
    int d = chunk / (8000 * 32);
    const float* src = (d ? Wb : Wf) + (size_t)v * 256 + kc;
    u16 t8[8];
    #pragma unroll
    for (int j = 0; j < 8; ++j) t8[j] = f2bf(src[j]);
    *(short8v*)(out + ((size_t)d * 8000 + v) * 256 + kc) = *(short8v*)t8;
}

// WdecBF[d][r][k]: k<256 -> Whh[r][k], else Wih[r][k-256]
__global__ __launch_bounds__(256) void k_wdecbf(const float* __restrict__ fWhh, const float* __restrict__ fWih,
                                                const float* __restrict__ bWhh, const float* __restrict__ bWih,
                                                u16* __restrict__ out) {
    int chunk = blockIdx.x * 256 + threadIdx.x;   // 2*1024*64 = 131072
    int kc = (chunk & 63) << 3;
    int r = (chunk >> 6) & 1023;
    int d = chunk >> 16;
    const float* Whh = d ? bWhh : fWhh;
    const float* Wih = d ? bWih : fWih;
    const float* src = (kc < 256) ? (Whh + (size_t)r * 256 + kc) : (Wih + (size_t)r * 256 + (kc - 256));
    u16 t8[8];
    #pragma unroll
    for (int j = 0; j < 8; ++j) t8[j] = f2bf(src[j]);
    *(short8v*)(out + ((size_t)d * 1024 + r) * 512 + kc) = *(short8v*)t8;
}

// encW[r][k]: k<256 -> enc_Whh[r][k], else enc_Wih[r][k-256]
__global__ __launch_bounds__(256) void k_wencbf(const float* __restrict__ Whh, const float* __restrict__ Wih,
                                                u16* __restrict__ out) {
    int chunk = blockIdx.x * 256 + threadIdx.x;   // 1024*64 = 65536
    int kc = (chunk & 63) << 3;
    int r = chunk >> 6;
    const float* src = (kc < 256) ? (Whh + (size_t)r * 256 + kc) : (Wih + (size_t)r * 256 + (kc - 256));
    u16 t8[8];
    #pragma unroll
    for (int j = 0; j < 8; ++j) t8[j] = f2bf(src[j]);
    *(short8v*)(out + (size_t)r * 512 + kc) = *(short8v*)t8;
}

// xEncBF[d][t][b][k] = bf16(emb[tok]), tok = t==0 ? 0 : (fwd S[b][t-1] / bwd S[b][128-t])
__global__ __launch_bounds__(256) void k_xenc(const int* __restrict__ S, const float* __restrict__ emb,
                                              u16* __restrict__ out) {
    int chunk = blockIdx.x * 256 + threadIdx.x;   // 2*128*16*32 = 131072
    int kc = (chunk & 31) << 3;
    int b = (chunk >> 5) & 15;
    int t = (chunk >> 9) & 127;
    int d = chunk >> 16;
    int tok = 0;
    if (t > 0) tok = d ? S[b * 128 + 128 - t] : S[b * 128 + t - 1];
    const float* src = emb + (size_t)tok * 256 + kc;
    u16 t8[8];
    #pragma unroll
    for (int j = 0; j < 8; ++j) t8[j] = f2bf(src[j]);
    *(short8v*)(out + (size_t)(((d * 128 + t) * 16) + b) * 256 + kc) = *(short8v*)t8;
}

__global__ __launch_bounds__(256) void k_decx(const int* __restrict__ S, const float* __restrict__ emb,
                                              u16* __restrict__ decX, int* __restrict__ winTok) {
    int chunk = blockIdx.x * 256 + threadIdx.x;   // 2*3*2048*32 = 393216
    int kc = (chunk & 31) << 3;
    int n = (chunk >> 5) & 2047;
    int r2 = chunk >> 16;
    int s = r2 % 3, d = r2 / 3;
    int b = n >> 7, tq = n & 127;
    int pos = min(tq + s, 127);
    int tok = d ? S[b * 128 + 127 - pos] : S[b * 128 + pos];
    const float* src = emb + (size_t)tok * 256 + kc;
    u16 t8[8];
    #pragma unroll
    for (int j = 0; j < 8; ++j) t8[j] = f2bf(src[j]);
    *(short8v*)(decX + ((size_t)(d * 3 + s) * NN + n) * 256 + kc) = *(short8v*)t8;
    if ((chunk & 31) == 0) winTok[(d * 3 + s) * NN + n] = tok;
}

// xp0[d][r] = emb[PART=0] . dec_Wih_d[r]  (f32, exact)
__global__ __launch_bounds__(256) void k_xp0(const float* __restrict__ emb,
                                             const float* __restrict__ Wihf,
                                             const float* __restrict__ Wihb,
                                             float* __restrict__ xp0) {
    int idx = blockIdx.x * 256 + threadIdx.x;  // 2048
    int d = idx >> 10, r = idx & 1023;
    const float* Wih = d ? Wihb : Wihf;
    float acc = 0.0f;
    for (int k = 0; k < 256; ++k) acc = fmaf(emb[k], Wih[r * 256 + k], acc);
    xp0[idx] = acc;
}

// ---------------- encoder x-projection GEMM: xprojb[d][n][r] = xEnc.Wih^T + bih + bhh ----------------
__global__ __launch_bounds__(256) void k_xproj(const u16* __restrict__ xEncBF,
                                               const u16* __restrict__ encW,
                                               const float* __restrict__ ebih,
                                               const float* __restrict__ ebhh,
                                               float* __restrict__ xprojb) {
    __shared__ u16 At[128 * 256];
    __shared__ u16 Bt[128 * 256];
    const int tid = threadIdx.x, lane = tid & 63, wid = tid >> 6;
    const int wm = wid >> 1, wv = wid & 1;
    const int r0 = blockIdx.x * 128, n0 = blockIdx.y * 128, d = blockIdx.z;
    stage128x256(xEncBF + (size_t)d * 2048 * 256, n0, 1 << 30, 256, 0, At, tid);
    stage128x256(encW, r0, 1 << 30, 512, 256, Bt, tid);
    __syncthreads();
    float4v acc[4][4];
    #pragma unroll
    for (int m = 0; m < 4; ++m)
        #pragma unroll
        for (int v = 0; v < 4; ++v) acc[m][v] = (float4v){0.f, 0.f, 0.f, 0.f};
    #pragma unroll
    for (int k = 0; k < 8; ++k) {
        short8v af[4], bf[4];
        #pragma unroll
        for (int m = 0; m < 4; ++m) af[m] = ldfrag(At, wm * 64 + m * 16, k * 32, lane, 512);
        #pragma unroll
        for (int v = 0; v < 4; ++v) bf[v] = ldfrag(Bt, wv * 64 + v * 16, k * 32, lane, 512);
        #pragma unroll
        for (int m = 0; m < 4; ++m)
            #pragma unroll
            for (int v = 0; v < 4; ++v)
                acc[m][v] = __builtin_amdgcn_mfma_f32_16x16x32_bf16(af[m], bf[v], acc[m][v], 0, 0, 0);
    }
    float bs[4]; int rg[4];
    #pragma unroll
    for (int v = 0; v < 4; ++v) {
        rg[v] = r0 + wv * 64 + v * 16 + (lane & 15);
        bs[v] = ebih[rg[v]] + ebhh[rg[v]];
    }
    #pragma unroll
    for (int m = 0; m < 4; ++m)
        #pragma unroll
        for (int i = 0; i < 4; ++i) {
            int n = n0 + wm * 64 + m * 16 + ((lane >> 4) << 2) + i;
            #pragma unroll
            for (int v = 0; v < 4; ++v)
                xprojb[((size_t)d * 2048 + n) * 1024 + rg[v]] = acc[m][v][i] + bs[v];
        }
}

// ---------------- persistent encoder: 8 blocks, Whh in VGPRs, flag barrier ----------------
__global__ __launch_bounds__(256) void k_enc2(const u16* __restrict__ encW,
                                              const float* __restrict__ xprojb,
                                              u16* __restrict__ hEncBF,
                                              float* __restrict__ h0dec,
                                              u16* __restrict__ h0bf,
                                              int* __restrict__ flags) {
    __shared__ u16 Ah[16 * 256];       // swizzled h tile, rowbytes 512
    __shared__ float gl[16 * 256];     // [b][gate*64 + unit_local]
    const int tid = threadIdx.x, lane = tid & 63, w = tid >> 6;
    const int blk = blockIdx.x, d = blk >> 2, u0 = (blk & 3) << 6;
    // Whh fragments pinned in registers: wave w = gate w, 64 units u0..u0+63
    short8v breg[4][8];
    #pragma unroll
    for (int c = 0; c < 4; ++c)
        #pragma unroll
        for (int kf = 0; kf < 8; ++kf)
            breg[c][kf] = *(const short8v*)(encW +
                (size_t)(w * 256 + u0 + c * 16 + (lane & 15)) * 512 + kf * 32 + ((lane >> 4) << 3));
    float creg[4] = {0.f, 0.f, 0.f, 0.f};
    const int cb = tid >> 4, cu = (tid & 15) << 2;
    for (int t = 0; t < 128; ++t) {
        int par = t & 1;
        const unsigned long long* hsrc =
            (const unsigned long long*)(hEncBF + (size_t)(par * 2 + d) * 4096);
        #pragma unroll
        for (int l = 0; l < 4; ++l) {
            int i = tid + l * 256;     // 1024 x 8B = 8KB
            unsigned long long v = __hip_atomic_load(&hsrc[i], __ATOMIC_RELAXED, __HIP_MEMORY_SCOPE_AGENT);
            int e = i << 2; int b = e >> 8, k = e & 255;
            int off = (b * 512 + k * 2) ^ ((b & 7) << 4);
            *(unsigned long long*)((char*)Ah + off) = v;
        }
        __syncthreads();
        // acc preloaded with x-projection + biases
        const float* xp = xprojb + ((size_t)d * 2048 + t * 16) * 1024 + w * 256 + u0 + (lane & 15);
        float4v acc[4];
        #pragma unroll
        for (int c = 0; c < 4; ++c)
            #pragma unroll
            for (int i = 0; i < 4; ++i)
                acc[c][i] = xp[(size_t)((((lane >> 4) << 2) + i)) * 1024 + c * 16];
        #pragma unroll
        for (int kf = 0; kf < 8; ++kf) {
            short8v af = ldfrag(Ah, 0, kf * 32, lane, 512);
            #pragma unroll
            for (int c = 0; c < 4; ++c)
                acc[c] = __builtin_amdgcn_mfma_f32_16x16x32_bf16(af, breg[c][kf], acc[c], 0, 0, 0);
        }
        #pragma unroll
        for (int c = 0; c < 4; ++c)
            #pragma unroll
            for (int i = 0; i < 4; ++i)
                gl[((((lane >> 4) << 2) + i) << 8) + (w << 6) + c * 16 + (lane & 15)] = acc[c][i];
        __syncthreads();
        u16 hl[4];
        #pragma unroll
        for (int q = 0; q < 4; ++q) {
            int ul = cu + q;
            float gi = gl[(cb << 8) + ul];
            float gf = gl[(cb << 8) + 64 + ul];
            float gg = gl[(cb << 8) + 128 + ul];
            float go = gl[(cb << 8) + 192 + ul];
            float cn = sigf(gf) * creg[q] + sigf(gi) * tanhsafe(gg);
            float h = sigf(go) * tanhsafe(cn);
            creg[q] = cn;
            size_t ni = ((size_t)d * NN + cb * 128 + t) * 256 + u0 + ul;
            h0dec[ni] = h;
            h0bf[ni] = f2bf(h);
            hl[q] = f2bf(h);
        }
        unsigned int* hdst = (unsigned int*)(hEncBF + (size_t)((par ^ 1) * 2 + d) * 4096);
        int ei = (cb * 256 + u0 + cu) >> 1;
        __hip_atomic_store(&hdst[ei], (unsigned int)hl[0] | ((unsigned int)hl[1] << 16),
                           __ATOMIC_RELAXED, __HIP_MEMORY_SCOPE_AGENT);
        __hip_atomic_store(&hdst[ei + 1], (unsigned int)hl[2] | ((unsigned int)hl[3] << 16),
                           __ATOMIC_RELAXED, __HIP_MEMORY_SCOPE_AGENT);
        __syncthreads();   // drains stores (compiler emits vmcnt(0) before barrier)
        if (tid == 0)
            __hip_atomic_store(&flags[blk * 32], t + 1, __ATOMIC_RELEASE, __HIP_MEMORY_SCOPE_AGENT);
        if (tid < 8)
            while (__hip_atomic_load(&flags[tid * 32], __ATOMIC_ACQUIRE, __HIP_MEMORY_SCOPE_AGENT) < t + 1)
                __builtin_amdgcn_s_sleep(1);
        __syncthreads();
    }
}

// ---------------- decoder gate GEMM (MFMA, 128x128 tile, K phases) ----------------
__global__ __launch_bounds__(256) void k_decmm(const u16* __restrict__ Ah, size_t ahStride,
                                               const u16* __restrict__ Axx, size_t axStride,
                                               const u16* __restrict__ Wdec,
                                               const float* __restrict__ bihf, const float* __restrict__ bhhf,
                                               const float* __restrict__ bihb, const float* __restrict__ bhhb,
                                               const float* __restrict__ xp0, int useX,
                                               float* __restrict__ gBuf) {
    __shared__ u16 At[128 * 256];
    __shared__ u16 Bt[128 * 256];
    const int tid = threadIdx.x, lane = tid & 63, wid = tid >> 6;
    const int wm = wid >> 1, wv = wid & 1;
    const int r0 = blockIdx.x * 128, n0 = blockIdx.y * 128, d = blockIdx.z;
    float4v acc[4][4];
    #pragma unroll
    for (int m = 0; m < 4; ++m)
        #pragma unroll
        for (int v = 0; v < 4; ++v) acc[m][v] = (float4v){0.f, 0.f, 0.f, 0.f};
    const int nph = useX ? 2 : 1;
    for (int ph = 0; ph < nph; ++ph) {
        const u16* Asrc = (ph == 0) ? (Ah + (size_t)d * ahStride) : (Axx + (size_t)d * axStride);
        stage128x256(Asrc, n0, 1 << 30, 256, 0, At, tid);
        stage128x256(Wdec + (size_t)d * 1024 * 512, r0, 1 << 30, 512, ph * 256, Bt, tid);
        __syncthreads();
        #pragma unroll
        for (int k = 0; k < 8; ++k) {
            short8v af[4], bf[4];
            #pragma unroll
            for (int m = 0; m < 4; ++m) af[m] = ldfrag(At, wm * 64 + m * 16, k * 32, lane, 512);
            #pragma unroll
            for (int v = 0; v < 4; ++v) bf[v] = ldfrag(Bt, wv * 64 + v * 16, k * 32, lane, 512);
            #pragma unroll
            for (int m = 0; m < 4; ++m)
                #pragma unroll
                for (int v = 0; v < 4; ++v)
                    acc[m][v] = __builtin_amdgcn_mfma_f32_16x16x32_bf16(af[m], bf[v], acc[m][v], 0, 0, 0);
        }
        __syncthreads();
    }
    const float* bih = d ? bihb : bihf;
    const float* bhh = d ? bhhb : bhhf;
    float bs[4]; int rg[4];
    #pragma unroll
    for (int v = 0; v < 4; ++v) {
        rg[v] = r0 + wv * 64 + v * 16 + (lane & 15);
        bs[v] = bih[rg[v]] + bhh[rg[v]];
        if (!useX) bs[v] += xp0[d * 1024 + rg[v]];
    }
    #pragma unroll
    for (int m = 0; m < 4; ++m)
        #pragma unroll
        for (int i = 0; i < 4; ++i) {
            int n = n0 + wm * 64 + m * 16 + ((lane >> 4) << 2) + i;
            #pragma unroll
            for (int v = 0; v < 4; ++v)
                gBuf[((size_t)d * NN + n) * 1024 + rg[v]] = acc[m][v][i] + bs[v];
        }
}

// ---------------- decoder cell ----------------
__global__ __launch_bounds__(256) void k_deccell(const float* __restrict__ gBuf,
                                                 const float* __restrict__ h0dec,
                                                 float* __restrict__ cDec,
                                                 u16* __restrict__ hsBF, int s) {
    int flat = blockIdx.x * 256 + threadIdx.x;  // 2*2048*256
    int j = flat & 255;
    int n = (flat >> 8) & 2047;
    int d = flat >> 19;
    const float* g = gBuf + ((size_t)d * NN + n) * 1024;
    float gi = g[j], gf = g[j + 256], gg = g[j + 512], go = g[j + 768];
    float cprev = (s == 0) ? h0dec[flat] : cDec[flat];
    float cn = sigf(gf) * cprev + sigf(gi) * tanhsafe(gg);
    float h = sigf(go) * tanhsafe(cn);
    cDec[flat] = cn;
    hsBF[((size_t)(d * 4 + s) * NN + n) * 256 + j] = f2bf(h);
}

// ---------------- projection: 512 thr, B-resident, s-loop, pipelined A halves ----------------
__global__ __launch_bounds__(512) void k_proj2(const u16* __restrict__ hsBF,
                                               const u16* __restrict__ WpBF,
                                               const float* __restrict__ bpf, const float* __restrict__ bpb,
                                               const int* __restrict__ winTok,
                                               float* __restrict__ partials,
                                               float* __restrict__ gchar, float* __restrict__ gtag) {
    __shared__ u16 Bt[128 * 256];        // 64KB, rowbytes 512
    __shared__ u16 Abuf0[128 * 128];     // 32KB, rowbytes 256
    __shared__ u16 Abuf1[128 * 128];     // 32KB
    const int tid = threadIdx.x, lane = tid & 63, w = tid >> 6;
    const int wm = w >> 1, wv = w & 1;   // 4m x 2v waves
    const int vt = blockIdx.x, n0 = blockIdx.y * 128, d = blockIdx.z;
    const int v0 = vt * 128;
    const float* bp = d ? bpb : bpf;
    float bpv[4]; int vg[4];
    #pragma unroll
    for (int v = 0; v < 4; ++v) {
        vg[v] = v0 + wv * 64 + v * 16 + (lane & 15);
        bpv[v] = (vg[v] < VOCAB) ? bp[vg[v]] : 0.0f;
    }

#define LOADA(s_, h_) do {                                                        \
        const u16* hsA = hsBF + (size_t)(d * 4 + (s_)) * NN * 256;                \
        _Pragma("unroll")                                                         \
        for (int it = 0; it < 4; ++it) {                                          \
            int g = tid + it * 512; int r = g >> 4, kc = (g & 15) << 3;           \
            areg[it] = *(const short8v*)(hsA + (size_t)(n0 + r) * 256 + (h_) * 128 + kc); \
        }                                                                         \
    } while (0)
#define WRITEA(bufp) do {                                                         \
        _Pragma("unroll")                                                         \
        for (int it = 0; it < 4; ++it) {                                          \
            int g = tid + it * 512; int r = g >> 4, kc = (g & 15) << 3;           \
            int off = (r * 256 + kc * 2) ^ ((r & 7) << 4);                        \
            *(short8v*)((char*)(bufp) + off) = areg[it];                          \
        }                                                                         \
    } while (0)
#define COMPUTE(bufp, h_) do {                                                    \
        _Pragma("unroll")                                                         \
        for (int kk = 0; kk < 4; ++kk) {                                          \
            short8v af[2], bf[4];                                                 \
            _Pragma("unroll")                                                     \
            for (int m = 0; m < 2; ++m) af[m] = ldfrag((bufp), wm * 32 + m * 16, kk * 32, lane, 256); \
            _Pragma("unroll")                                                     \
            for (int v = 0; v < 4; ++v) bf[v] = ldfrag(Bt, wv * 64 + v * 16, (h_) * 128 + kk * 32, lane, 512); \
            _Pragma("unroll")                                                     \
            for (int m = 0; m < 2; ++m)                                           \
                _Pragma("unroll")                                                 \
                for (int v = 0; v < 4; ++v)                                       \
                    acc[m][v] = __builtin_amdgcn_mfma_f32_16x16x32_bf16(af[m], bf[v], acc[m][v], 0, 0, 0); \
        }                                                                         \
    } while (0)

    // stage B (Wp tile) to regs then swizzled LDS
    short8v bregs[8];
    #pragma unroll
    for (int it = 0; it < 8; ++it) {
        int g = tid + it * 512; int r = g >> 5, kc = (g & 31) << 3;
        int vv = v0 + r;
        if (vv < VOCAB) bregs[it] = *(const short8v*)(WpBF + ((size_t)d * 8000 + vv) * 256 + kc);
        else bregs[it] = (short8v){0, 0, 0, 0, 0, 0, 0, 0};
    }
    short8v areg[4];
    LOADA(0, 0);
    #pragma unroll
    for (int it = 0; it < 8; ++it) {
        int g = tid + it * 512; int r = g >> 5, kc = (g & 31) << 3;
        int off = (r * 512 + kc * 2) ^ ((r & 7) << 4);
        *(short8v*)((char*)Bt + off) = bregs[it];
    }
    WRITEA(Abuf0);
    __syncthreads();
    LOADA(0, 1);

    for (int s = 0; s < 4; ++s) {
        float4v acc[2][4];
        #pragma unroll
        for (int m = 0; m < 2; ++m)
            #pragma unroll
            for (int v = 0; v < 4; ++v) acc[m][v] = (float4v){0.f, 0.f, 0.f, 0.f};
        COMPUTE(Abuf0, 0);
        __syncthreads();
        WRITEA(Abuf1);
        __syncthreads();
        if (s < 3) LOADA(s + 1, 0);
        COMPUTE(Abuf1, 1);
        // epilogue: bias, capture, LSE over 64-col half
        #pragma unroll
        for (int m = 0; m < 2; ++m)
            #pragma unroll
            for (int i = 0; i < 4; ++i) {
                int n = n0 + wm * 32 + m * 16 + ((lane >> 4) << 2) + i;
                int tok = (s < 3) ? winTok[(d * 3 + s) * NN + n] : -1;
                float lg[4];
                #pragma unroll
                for (int v = 0; v < 4; ++v) {
                    lg[v] = (vg[v] < VOCAB) ? acc[m][v][i] + bpv[v] : -1e30f;
                    if (vg[v] == tok) gchar[(d * 3 + s) * NN + n] = lg[v];
                    if (s >= 1 && vg[v] == 0) gtag[(d * 3 + (s - 1)) * NN + n] = lg[v];
                }
                float mx = fmaxf(fmaxf(lg[0], lg[1]), fmaxf(lg[2], lg[3]));
                #pragma unroll
                for (int off = 1; off <= 8; off <<= 1) mx = fmaxf(mx, __shfl_xor(mx, off));
                float sum = 0.0f;
                #pragma unroll
                for (int v = 0; v < 4; ++v) sum += (lg[v] > -1e29f) ? __expf(lg[v] - mx) : 0.0f;
                #pragma unroll
                for (int off = 1; off <= 8; off <<= 1) sum += __shfl_xor(sum, off);
                if ((lane & 15) == 0)
                    partials[((size_t)(d * 4 + s) * NN + n) * 126 + vt * 2 + wv] = mx + __logf(sum);
            }
        __syncthreads();
        if (s < 3) {
            WRITEA(Abuf0);
            __syncthreads();
            LOADA(s + 1, 1);
        }
    }
#undef LOADA
#undef WRITEA
#undef COMPUTE
}

// ---------------- LSE reduce over 126 v-halves ----------------
__global__ __launch_bounds__(256) void k_lzred(const float* __restrict__ partials,
                                               float* __restrict__ logZ) {
    int wid = threadIdx.x >> 6, lane = threadIdx.x & 63;
    int row = blockIdx.x * 4 + wid;  // 0..16383
    const float* p = partials + (size_t)row * 126;
    float mx = p[lane];
    float sum = 1.0f;
    if (lane + 64 < 126) {
        float b = p[lane + 64];
        float M = fmaxf(mx, b);
        sum = __expf(mx - M) + __expf(b - M);
        mx = M;
    }
    #pragma unroll
    for (int off = 1; off <= 32; off <<= 1) {
        float m2 = __shfl_xor(mx, off);
        float s2 = __shfl_xor(sum, off);
        float M = fmaxf(mx, m2);
        sum = sum * __expf(mx - M) + s2 * __expf(m2 - M);
        mx = M;
    }
    if (lane == 0) logZ[row] = mx + __logf(sum);
}

// ---------------- P assembly ----------------
__global__ __launch_bounds__(256) void k_passm(const float* __restrict__ gchar,
                                               const float* __restrict__ gtag,
                                               const float* __restrict__ logZ,
                                               float* __restrict__ P) {
    int flat = blockIdx.x * 256 + threadIdx.x;  // 128*3*16
    if (flat >= 128 * 3 * 16) return;
    int b = flat & 15;
    int y = (flat >> 4) % 3;
    int x = flat / 48;
    int nf = b * 128 + min(127, max(0, x - y));
    int nb = b * 128 + 127 - x;
    float pf = 0.0f, pb = 0.0f;
    for (int ss = 0; ss <= y; ++ss) {
        pf += gchar[ss * NN + nf] - logZ[ss * NN + nf];
        pb += gchar[(3 + ss) * NN + nb] - logZ[(4 + ss) * NN + nb];
    }
    pf += gtag[y * NN + nf] - logZ[(y + 1) * NN + nf];
    pb += gtag[(3 + y) * NN + nb] - logZ[(4 + y + 1) * NN + nb];
    P[flat] = 0.5f * (pf + pb);
}

// ---------------- semi-CRF scan + loss ----------------
__global__ __launch_bounds__(64) void k_scan(const float* __restrict__ P, float* __restrict__ out) {
    __shared__ float buf[3][16];
    __shared__ float cand[3][16];
    __shared__ float tot[16];
    int tid = threadIdx.x;
    if (tid < 48) buf[tid / 16][tid % 16] = 0.0f;
    __syncthreads();
    for (int j = 1; j <= 128; ++j) {
        if (tid < 48) {
            int i = tid / 16, b = tid % 16;
            cand[i][b] = (i < j) ? buf[i][b] + P[((j - 1) * 3 + i) * 16 + b] : -1e30f;
        }
        __syncthreads();
        if (tid < 16) {
            int b = tid;
            float c0 = cand[0][b], c1 = cand[1][b], c2 = cand[2][b];
            float mx = fmaxf(c0, fmaxf(c1, c2));
            float sv = __expf(c0 - mx) + __expf(c1 - mx) + __expf(c2 - mx);
            float t_ = mx + __logf(sv);
            float b0 = buf[0][b], b1 = buf[1][b];
            buf[0][b] = t_; buf[1][b] = b0; buf[2][b] = b1;
            tot[b] = t_;
        }
        __syncthreads();
    }
    if (tid == 0) {
        float sacc = 0.0f;
        for (int b = 0; b < 16; ++b) sacc += tot[b];
        out[0] = -sacc / 16.0f;
    }
}

// ---------------- launch ----------------
extern "C" void kernel_launch(void* const* d_in, const int* in_sizes, int n_in,
                              void* d_out, int out_size, void* d_ws, size_t ws_size,
                              hipStream_t stream) {
    const int* S = (const int*)d_in[0];
    const float* emb = (const float*)d_in[1];
    const float* eWih = (const float*)d_in[2];
    const float* eWhh = (const float*)d_in[3];
    const float* ebih = (const float*)d_in[4];
    const float* ebhh = (const float*)d_in[5];
    const float* fWih = (const float*)d_in[6];
    const float* fWhh = (const float*)d_in[7];
    const float* fbih = (const float*)d_in[8];
    const float* fbhh = (const float*)d_in[9];
    const float* fWp  = (const float*)d_in[10];
    const float* fbp  = (const float*)d_in[11];
    const float* bWih = (const float*)d_in[12];
    const float* bWhh = (const float*)d_in[13];
    const float* bbih = (const float*)d_in[14];
    const float* bbhh = (const float*)d_in[15];
    const float* bWp  = (const float*)d_in[16];
    const float* bbp  = (const float*)d_in[17];

    float* w = (float*)d_ws;
    u16* WpBF    = (u16*)(w + OFF_WPBF);
    u16* WdecBF  = (u16*)(w + OFF_WDEC);
    u16* xEncBF  = (u16*)(w + OFF_XENC);
    u16* hEncBF  = (u16*)(w + OFF_HENCBF);
    float* h0dec = w + OFF_H0DEC;
    u16* h0bf    = (u16*)(w + OFF_H0BF);
    u16* decXBF  = (u16*)(w + OFF_DECX);
    float* cDec  = w + OFF_CDEC;
    u16* hsBF    = (u16*)(w + OFF_HSBF);
    float* gBuf  = w + OFF_GBUF;
    float* xprojb = gBuf;     // aliased: used only before decoder
    float* partials = gBuf;   // aliased: used only after decoder
    float* logZ  = w + OFF_LOGZ;
    float* gchar = w + OFF_GCH;
    float* gtag  = w + OFF_GTG;
    float* Pm    = w + OFF_P;
    int* winTok  = (int*)(w + OFF_WTOK);
    float* xp0   = w + OFF_XP0;
    u16* encW    = (u16*)(w + OFF_ENCW);
    int* flags   = (int*)(w + OFF_FLAGS);

    k_zero<<<32, 256, 0, stream>>>(w + OFF_HENCBF, 8192);
    k_zero<<<1, 256, 0, stream>>>(w + OFF_FLAGS, 256);
    k_wpbf<<<2000, 256, 0, stream>>>(fWp, bWp, WpBF);
    k_wdecbf<<<512, 256, 0, stream>>>(fWhh, fWih, bWhh, bWih, WdecBF);
    k_wencbf<<<256, 256, 0, stream>>>(eWhh, eWih, encW);
    k_xenc<<<512, 256, 0, stream>>>(S, emb, xEncBF);
    k_decx<<<1536, 256, 0, stream>>>(S, emb, decXBF, winTok);
    k_xp0<<<8, 256, 0, stream>>>(emb, fWih, bWih, xp0);

    k_xproj<<<dim3(8, 16, 2), 256, 0, stream>>>(xEncBF, encW, ebih, ebhh, xprojb);
    k_enc2<<<8, 256, 0, stream>>>(encW, xprojb, hEncBF, h0dec, h0bf, flags);

    for (int s = 0; s < 4; ++s) {
        const u16* Ah; size_t ahS;
        const u16* Axx; size_t axS;
        if (s == 0) {
            Ah = h0bf; ahS = (size_t)NN * 256;
            Axx = decXBF; axS = (size_t)3 * NN * 256;  // unused
        } else {
            Ah = hsBF + (size_t)(s - 1) * NN * 256; ahS = (size_t)4 * NN * 256;
            Axx = decXBF + (size_t)(s - 1) * NN * 256; axS = (size_t)3 * NN * 256;
        }
        k_decmm<<<dim3(8, 16, 2), 256, 0, stream>>>(Ah, ahS, Axx, axS, WdecBF,
                                                    fbih, fbhh, bbih, bbhh, xp0,
                                                    (s == 0) ? 0 : 1, gBuf);
        k_deccell<<<4096, 256, 0, stream>>>(gBuf, h0dec, cDec, hsBF, s);
    }

    k_proj2<<<dim3(63, 16, 2), 512, 0, stream>>>(hsBF, WpBF, fbp, bbp, winTok,
                                                 partials, gchar, gtag);
    k_lzred<<<4096, 256, 0, stream>>>(partials, logZ);
    k_passm<<<24, 256, 0, stream>>>(gchar, gtag, logZ, Pm);
    k_scan<<<1, 64, 0, stream>>>(Pm, (float*)d_out);
}